// Round 6
// baseline (196.537 us; speedup 1.0000x reference)
//
#include <hip/hip_runtime.h>
#include <hip/hip_bf16.h>

#define CC   128
#define HH_  64
#define WW_  64
#define BB   8
#define HWSZ (HH_*WW_)      // 4096
#define CHW  (CC*HWSZ)      // 524288
#define BCHW (BB*CHW)       // 4194304
#define PAD  3
#define NP   49

typedef __attribute__((ext_vector_type(8))) short short8;
typedef __attribute__((ext_vector_type(4))) float float4v;

// ============ Kernel 0: W -> bf16 hi/lo split (into d_out scratch) ==========
__global__ __launch_bounds__(256) void prep_w(
    const float* __restrict__ Wq, const float* __restrict__ Wk,
    const float* __restrict__ Wv,
    unsigned short* __restrict__ whi, unsigned short* __restrict__ wlo)
{
    int i = blockIdx.x * 256 + threadIdx.x;          // 0..49151
    const float* src = (i < 16384) ? Wq : (i < 32768 ? Wk : Wv);
    float f = src[i & 16383];
    __hip_bfloat16 h = __float2bfloat16(f);
    float hf = __bfloat162float(h);
    __hip_bfloat16 l = __float2bfloat16(f - hf);
    unsigned short hu, lu;
    __builtin_memcpy(&hu, &h, 2);
    __builtin_memcpy(&lu, &l, 2);
    whi[i] = hu;
    wlo[i] = lu;
}

// ============ Kernel 1: q/k/v GEMM via split-bf16 MFMA ======================
// xT column-block XOR swizzle: breaks the 16-way write conflict of the
// unswizzled layout (lane stride 272 dwords = 16 mod 32 banks).
__global__ __launch_bounds__(256, 2) void qkv_mfma(
    const float* __restrict__ x,
    const unsigned short* __restrict__ whi, const unsigned short* __restrict__ wlo,
    const float* __restrict__ bq, const float* __restrict__ bk,
    const float* __restrict__ bv, float* __restrict__ qkv)
{
    __shared__ unsigned short xT[2][128][136];   // [hi/lo][px][c swizzled]
    const int proj = blockIdx.y;
    const int n0g  = blockIdx.x << 7;
    const int b    = n0g >> 12;
    const int npx  = n0g & 4095;
    const int tid  = threadIdx.x;
    const int lane = tid & 63;
    const int wvu  = __builtin_amdgcn_readfirstlane(tid >> 6);   // wave id
    const int wm   = wvu & 1, wn = wvu >> 1;

    const float* xb = x + (size_t)b*CHW + npx;
    #pragma unroll
    for (int it = 0; it < 16; ++it) {
        int f  = tid + (it << 8);       // 0..4095
        int c  = f >> 5;                // 0..127
        int p4 = (f & 31) << 2;         // px quad
        int csw = (((c >> 3) ^ ((p4 >> 3) & 7)) << 3) | (c & 7);
        float4 v = *(const float4*)&xb[(size_t)c*HWSZ + p4];
        float vv[4] = {v.x, v.y, v.z, v.w};
        #pragma unroll
        for (int u = 0; u < 4; ++u) {
            __hip_bfloat16 h = __float2bfloat16(vv[u]);
            float hf = __bfloat162float(h);
            __hip_bfloat16 l = __float2bfloat16(vv[u] - hf);
            unsigned short hu, lu;
            __builtin_memcpy(&hu, &h, 2);
            __builtin_memcpy(&lu, &l, 2);
            xT[0][p4 + u][csw] = hu;
            xT[1][p4 + u][csw] = lu;
        }
    }

    const float* Bp = (proj == 0) ? bq : (proj == 1 ? bk : bv);
    const int q4 = lane >> 4;
    float4v acc[4][4];
    #pragma unroll
    for (int sm = 0; sm < 4; ++sm) {
        const int mb = wm*64 + sm*16 + q4*4;
        float4v bi;
        bi[0] = Bp[mb+0]; bi[1] = Bp[mb+1]; bi[2] = Bp[mb+2]; bi[3] = Bp[mb+3];
        #pragma unroll
        for (int sn = 0; sn < 4; ++sn) acc[sm][sn] = bi;
    }

    __syncthreads();

    const unsigned short* Wh = whi + (size_t)proj*16384;
    const unsigned short* Wl = wlo + (size_t)proj*16384;
    const int kq8  = q4 << 3;
    const int mrow = lane & 15;

    for (int pass = 0; pass < 3; ++pass) {
        const unsigned short* Wp = (pass == 2) ? Wl : Wh;
        const int xi = (pass == 1) ? 1 : 0;
        #pragma unroll
        for (int kc = 0; kc < 4; ++kc) {
            const int kb = kc << 5;
            short8 a[4], bf[4];
            #pragma unroll
            for (int sm = 0; sm < 4; ++sm) {
                const int m = wm*64 + sm*16 + mrow;
                a[sm] = *(const short8*)&Wp[(size_t)m*CC + kb + kq8];
            }
            #pragma unroll
            for (int sn = 0; sn < 4; ++sn) {
                const int n = wn*64 + sn*16 + mrow;
                const int scol = (kb + kq8) ^ (((n >> 3) & 7) << 3);
                bf[sn] = *(const short8*)&xT[xi][n][scol];
            }
            #pragma unroll
            for (int sm = 0; sm < 4; ++sm)
                #pragma unroll
                for (int sn = 0; sn < 4; ++sn)
                    acc[sm][sn] = __builtin_amdgcn_mfma_f32_16x16x32_bf16(
                        a[sm], bf[sn], acc[sm][sn], 0, 0, 0);
        }
    }

    float* op = qkv + (size_t)proj*BCHW + (size_t)b*CHW + npx;
    #pragma unroll
    for (int sm = 0; sm < 4; ++sm) {
        const int mb = wm*64 + sm*16 + q4*4;
        #pragma unroll
        for (int sn = 0; sn < 4; ++sn) {
            const int n = wn*64 + sn*16 + mrow;
            #pragma unroll
            for (int r = 0; r < 4; ++r)
                op[(size_t)(mb + r)*HWSZ + n] = acc[sm][sn][r];
        }
    }
}

// ================= Kernel 2: local attention v9 =============================
// v8 (136.7us total, locatt ~38) + three latency/VALU cuts, math untouched:
//  1. Phase C per-chunk __syncthreads DELETED: wave s stores AND reads only
//     channels {2s,2s+1} at its own lanes' pixel window -> staging is purely
//     intra-wave; s_waitcnt lgkmcnt(0) suffices. 8 fewer full-block barriers
//     and (critically) no vmcnt(0) drain of the v-prefetch.
//  2. wave id via readfirstlane -> SGPR: scalarizes k-row LDS bases, v-load
//     and out-store addressing (saddr+voffset form instead of 64b VGPR math).
//  3. stg/vreg ping-pong (full unroll, compile-time idx) removes the WAR
//     between ds_write register consumption and the next global prefetch.
__device__ __forceinline__ void load_chunk8(const float* __restrict__ src,
                                            int h0, int c0, float4* stg) {
    const int tid = threadIdx.x;
    #pragma unroll
    for (int i = 0; i < 4; ++i) {
        int f   = tid + (i << 9);           // 0..2047 = 16ch * 8r * 16quads
        int c   = f >> 7;
        int rem = f & 127;
        int r   = rem >> 4;
        int q4  = (rem & 15) << 2;
        int hh  = h0 - PAD + r;
        if ((unsigned)hh < (unsigned)HH_)
            stg[i] = *(const float4*)&src[(size_t)(c0 + c)*HWSZ + hh*WW_ + q4];
        else
            stg[i] = make_float4(0.f, 0.f, 0.f, 0.f);
    }
}

__global__ __launch_bounds__(512) void locatt(
    const float* __restrict__ qkv, float* __restrict__ out)
{
    __shared__ __align__(16) float smem[2*9792];    // A: +0/+9216, C: +0/+9792
    __shared__ float lg[2][NP][64];                 // 25088 B
    __shared__ float dn[2][64];

    const int blk = blockIdx.x;
    const int xs  = blk & 7;
    const int jj  = blk >> 3;
    const int b   = jj >> 2;
    const int h0  = (((xs << 2) | (jj & 3)) << 1);
    const int tid = threadIdx.x;
    const int su  = __builtin_amdgcn_readfirstlane(tid >> 6);   // wave 0..7
    const int lane = tid & 63;
    const int q16  = lane & 15;
    const int csub = lane >> 4;
    const int w4   = q16 << 2;
    const int w    = lane;         // phase C pixel

    const float* qp = qkv + (size_t)b*CHW;
    const float* kp = qkv + (size_t)BCHW + (size_t)b*CHW;
    const float* vp = qkv + (size_t)2*BCHW + (size_t)b*CHW;

    // zero k halo cols (0-3 & 68-71) in BOTH A-buffers; staging writes only
    // cols 4..67, so halos persist for all of phase A.
    {
        int buf = tid >> 8;                 // 0..1
        int t2  = tid & 255;
        int idx = t2 & 127;
        int c = idx >> 3, r = idx & 7;
        int col = (t2 < 128) ? 0 : 68;
        *(float4*)&smem[buf*9216 + (c*8 + r)*72 + col] =
            make_float4(0.f, 0.f, 0.f, 0.f);
    }

    const bool do0 = (su < 7);   // k-row su serves row0 p = su*7+dx
    const bool do1 = (su >= 1);  // and row1 p = (su-1)*7+dx

    float acc0[7][4], acc1[7][4];
    #pragma unroll
    for (int dx = 0; dx < 7; ++dx)
        #pragma unroll
        for (int j = 0; j < 4; ++j) { acc0[dx][j] = 0.f; acc1[dx][j] = 0.f; }

    float4 stg[2][4];
    load_chunk8(kp, h0, 0, stg[0]);

    // -------- Phase A (double-buffered, 1 barrier/chunk) --------
    #pragma unroll
    for (int ck = 0; ck < 8; ++ck) {
        float* ksb = smem + (ck & 1)*9216;      // [16][8][72]
        float4* sc = stg[ck & 1];
        #pragma unroll
        for (int i = 0; i < 4; ++i) {
            int f   = tid + (i << 9);
            int c   = f >> 7;
            int rem = f & 127;
            int r   = rem >> 4;
            int q4  = (rem & 15) << 2;
            *(float4*)&ksb[(c*8 + r)*72 + 4 + q4] = sc[i];
        }
        __syncthreads();
        if (ck < 7) load_chunk8(kp, h0, (ck + 1) * 16, stg[(ck + 1) & 1]);

        const int c0 = ck << 4;
        #pragma unroll
        for (int ci4 = 0; ci4 < 4; ++ci4) {
            const int c = (ci4 << 2) + csub;
            const float* qc = qp + (size_t)(c0 + c)*HWSZ + h0*WW_ + w4;
            float4 q0v = do0 ? *(const float4*)qc
                             : make_float4(0.f, 0.f, 0.f, 0.f);
            float4 q1v = do1 ? *(const float4*)(qc + WW_)
                             : make_float4(0.f, 0.f, 0.f, 0.f);
            const float* krow = &ksb[(c*8 + su)*72];
            float4 ka  = *(const float4*)&krow[w4];
            float4 kb  = *(const float4*)&krow[w4 + 4];
            float4 kc2 = *(const float4*)&krow[w4 + 8];
            float kw[12] = {ka.x,ka.y,ka.z,ka.w, kb.x,kb.y,kb.z,kb.w,
                            kc2.x,kc2.y,kc2.z,kc2.w};
            float q0a[4] = {q0v.x,q0v.y,q0v.z,q0v.w};
            float q1a[4] = {q1v.x,q1v.y,q1v.z,q1v.w};
            #pragma unroll
            for (int dx = 0; dx < 7; ++dx)
                #pragma unroll
                for (int j = 0; j < 4; ++j) {
                    float kv = kw[j + dx + 1];   // spatial w4+j+dx-3
                    acc0[dx][j] = fmaf(q0a[j], kv, acc0[dx][j]);
                    acc1[dx][j] = fmaf(q1a[j], kv, acc1[dx][j]);
                }
        }
        // no trailing barrier: next chunk stores into the other buffer
    }

    // cross-csub reduce (lanes 0..15 <-> 16..31 <-> 32..47 <-> 48..63)
    #pragma unroll
    for (int dx = 0; dx < 7; ++dx)
        #pragma unroll
        for (int j = 0; j < 4; ++j) {
            acc0[dx][j] += __shfl_xor(acc0[dx][j], 16, 64);
            acc0[dx][j] += __shfl_xor(acc0[dx][j], 32, 64);
            acc1[dx][j] += __shfl_xor(acc1[dx][j], 16, 64);
            acc1[dx][j] += __shfl_xor(acc1[dx][j], 32, 64);
        }
    // write lg (b128), distributed: csub writes dx with (dx&3)==csub
    #pragma unroll
    for (int dx = 0; dx < 7; ++dx) {
        if ((dx & 3) == csub) {
            if (do0) *(float4*)&lg[0][su*7 + dx][w4] =
                make_float4(acc0[dx][0], acc0[dx][1], acc0[dx][2], acc0[dx][3]);
            if (do1) *(float4*)&lg[1][(su-1)*7 + dx][w4] =
                make_float4(acc1[dx][0], acc1[dx][1], acc1[dx][2], acc1[dx][3]);
        }
    }

    // prefetch v chunk 0 (wave su -> chunk channels {2su,2su+1}, all 8 rows)
    float vreg[2][16];
    {
        #pragma unroll
        for (int i = 0; i < 16; ++i) {
            int c  = 2*su + (i >> 3);
            int r  = i & 7;
            int hh = h0 - PAD + r;
            vreg[0][i] = ((unsigned)hh < (unsigned)HH_)
                         ? vp[(size_t)c*HWSZ + hh*WW_ + w] : 0.f;
        }
    }
    __syncthreads();

    // -------- Phase B: two softmaxes (OOB logits exactly 0, included) ------
    if (tid < 128) {
        const int r = tid >> 6, px = tid & 63;
        float tv[NP];
        float m = -1e30f;
        #pragma unroll
        for (int p = 0; p < NP; ++p) { tv[p] = lg[r][p][px]; m = fmaxf(m, tv[p]); }
        float d = 0.f;
        #pragma unroll
        for (int p = 0; p < NP; ++p) {
            float e = __expf(tv[p] - m);
            d += e;
            lg[r][p][px] = e;
        }
        dn[r][px] = 1.f / d;
    } else {
        // zero vT halo cols {0..3, 68..71} x 8r x 16 slots in BOTH C-buffers
        // (2048 floats over threads 128..511)
        int t = tid - 128;
        for (int i = t; i < 2048; i += 384) {
            int buf  = i >> 10;
            int rem1 = i & 1023;
            int r    = rem1 >> 7;
            int rem  = rem1 & 127;
            int colg = rem >> 4;
            int col  = (colg < 4) ? colg : (64 + colg);
            smem[buf*9792 + r*1224 + col*17 + (rem & 15)] = 0.f;
        }
    }
    __syncthreads();

    // -------- Phase C (barrier-free: staging is intra-wave only) --------
    float a0[NP], a1[NP];
    const float sc0 = dn[0][w], sc1 = dn[1][w];
    #pragma unroll
    for (int p = 0; p < NP; ++p) a0[p] = lg[0][p][w] * sc0;
    #pragma unroll
    for (int p = 0; p < NP; ++p) a1[p] = lg[1][p][w] * sc1;

    #pragma unroll
    for (int ck = 0; ck < 8; ++ck) {
        float* vb = smem + (ck & 1)*9792;       // vT[8][72][17]
        float* vc = vreg[ck & 1];
        // store vreg -> vT[r][4+w][c]  (stride 17 across lanes: conflict-free)
        #pragma unroll
        for (int i = 0; i < 16; ++i) {
            int c = 2*su + (i >> 3);
            int r = i & 7;
            vb[r*1224 + (4 + w)*17 + c] = vc[i];
        }
        if (ck < 7) {
            int c0v = (ck + 1) << 4;
            float* vn = vreg[(ck + 1) & 1];
            #pragma unroll
            for (int i = 0; i < 16; ++i) {
                int c  = 2*su + (i >> 3);
                int r  = i & 7;
                int hh = h0 - PAD + r;
                vn[i] = ((unsigned)hh < (unsigned)HH_)
                        ? vp[(size_t)(c0v + c)*HWSZ + hh*WW_ + w] : 0.f;
            }
        }
        // intra-wave LDS visibility only: wave su wrote channels {2su,2su+1}
        // and reads exactly those channels at its own lanes' pixel window.
        asm volatile("s_waitcnt lgkmcnt(0)" ::: "memory");

        float y0a = 0.f, y0b = 0.f, y1a = 0.f, y1b = 0.f;
        #pragma unroll
        for (int r = 0; r < 8; ++r) {
            const float* vbase = &vb[r*1224 + (1 + w)*17 + 2*su];
            #pragma unroll
            for (int dx = 0; dx < 7; ++dx) {
                float va  = vbase[17*dx];       // channel 2su
                float vb2 = vbase[17*dx + 1];   // channel 2su+1 (ds_read2 pair)
                if (r < 7) {
                    float aw = a0[r*7 + dx];
                    y0a = fmaf(aw, va, y0a); y0b = fmaf(aw, vb2, y0b);
                }
                if (r >= 1) {
                    float aw = a1[(r-1)*7 + dx];
                    y1a = fmaf(aw, va, y1a); y1b = fmaf(aw, vb2, y1b);
                }
            }
        }
        float* op = out + (size_t)b*CHW + (size_t)(ck*16 + 2*su)*HWSZ
                        + (size_t)h0*WW_ + w;
        op[0]          = y0a;   // c=2su,   row h0
        op[WW_]        = y1a;   // c=2su,   row h0+1
        op[HWSZ]       = y0b;   // c=2su+1, row h0
        op[HWSZ + WW_] = y1b;   // c=2su+1, row h0+1
    }
}

extern "C" void kernel_launch(void* const* d_in, const int* in_sizes, int n_in,
                              void* d_out, int out_size, void* d_ws, size_t ws_size,
                              hipStream_t stream) {
    const float* x  = (const float*)d_in[0];
    const float* Wq = (const float*)d_in[1];
    const float* bq = (const float*)d_in[2];
    const float* Wk = (const float*)d_in[3];
    const float* bk = (const float*)d_in[4];
    const float* Wv = (const float*)d_in[5];
    const float* bv = (const float*)d_in[6];
    float* out = (float*)d_out;
    float* qkv = (float*)d_ws;   // 3*BCHW*4 = 50.3 MB scratch

    // d_out doubles as scratch for bf16 W (196 KB); fully overwritten by
    // locatt afterwards (stream-ordered), safe under re-poisoning.
    unsigned short* whi = (unsigned short*)d_out;
    unsigned short* wlo = whi + 3*16384;

    prep_w  <<<192, 256, 0, stream>>>(Wq, Wk, Wv, whi, wlo);
    qkv_mfma<<<dim3(256, 3), 256, 0, stream>>>(x, whi, wlo, bq, bk, bv, qkv);
    locatt  <<<256, 512, 0, stream>>>(qkv, out);
}

// Round 7
// 137.266 us; speedup vs baseline: 1.4318x; 1.4318x over previous
//
#include <hip/hip_runtime.h>
#include <hip/hip_bf16.h>

#define CC   128
#define HH_  64
#define WW_  64
#define BB   8
#define HWSZ (HH_*WW_)      // 4096
#define CHW  (CC*HWSZ)      // 524288
#define BCHW (BB*CHW)       // 4194304
#define PAD  3
#define NP   49

typedef __attribute__((ext_vector_type(8))) short short8;
typedef __attribute__((ext_vector_type(4))) float float4v;

// ============ Kernel 0: W -> bf16 hi/lo split (into d_out scratch) ==========
__global__ __launch_bounds__(256) void prep_w(
    const float* __restrict__ Wq, const float* __restrict__ Wk,
    const float* __restrict__ Wv,
    unsigned short* __restrict__ whi, unsigned short* __restrict__ wlo)
{
    int i = blockIdx.x * 256 + threadIdx.x;          // 0..49151
    const float* src = (i < 16384) ? Wq : (i < 32768 ? Wk : Wv);
    float f = src[i & 16383];
    __hip_bfloat16 h = __float2bfloat16(f);
    float hf = __bfloat162float(h);
    __hip_bfloat16 l = __float2bfloat16(f - hf);
    unsigned short hu, lu;
    __builtin_memcpy(&hu, &h, 2);
    __builtin_memcpy(&lu, &l, 2);
    whi[i] = hu;
    wlo[i] = lu;
}

// ============ Kernel 1: q/k/v GEMM via split-bf16 MFMA (R2/R5 version) ======
// xT column-block XOR swizzle: breaks the 16-way write conflict of the
// unswizzled layout (lane stride 272 dwords = 16 mod 32 banks).
__global__ __launch_bounds__(256, 2) void qkv_mfma(
    const float* __restrict__ x,
    const unsigned short* __restrict__ whi, const unsigned short* __restrict__ wlo,
    const float* __restrict__ bq, const float* __restrict__ bk,
    const float* __restrict__ bv, float* __restrict__ qkv)
{
    __shared__ unsigned short xT[2][128][136];   // [hi/lo][px][c swizzled]
    const int proj = blockIdx.y;
    const int n0g  = blockIdx.x << 7;
    const int b    = n0g >> 12;
    const int npx  = n0g & 4095;
    const int tid  = threadIdx.x;
    const int lane = tid & 63;
    const int wv   = tid >> 6;
    const int wm   = wv & 1, wn = wv >> 1;

    const float* xb = x + (size_t)b*CHW + npx;
    #pragma unroll
    for (int it = 0; it < 16; ++it) {
        int f  = tid + (it << 8);       // 0..4095
        int c  = f >> 5;                // 0..127
        int p4 = (f & 31) << 2;         // px quad
        int csw = (((c >> 3) ^ ((p4 >> 3) & 7)) << 3) | (c & 7);
        float4 v = *(const float4*)&xb[(size_t)c*HWSZ + p4];
        float vv[4] = {v.x, v.y, v.z, v.w};
        #pragma unroll
        for (int u = 0; u < 4; ++u) {
            __hip_bfloat16 h = __float2bfloat16(vv[u]);
            float hf = __bfloat162float(h);
            __hip_bfloat16 l = __float2bfloat16(vv[u] - hf);
            unsigned short hu, lu;
            __builtin_memcpy(&hu, &h, 2);
            __builtin_memcpy(&lu, &l, 2);
            xT[0][p4 + u][csw] = hu;
            xT[1][p4 + u][csw] = lu;
        }
    }

    const float* Bp = (proj == 0) ? bq : (proj == 1 ? bk : bv);
    const int q4 = lane >> 4;
    float4v acc[4][4];
    #pragma unroll
    for (int sm = 0; sm < 4; ++sm) {
        const int mb = wm*64 + sm*16 + q4*4;
        float4v bi;
        bi[0] = Bp[mb+0]; bi[1] = Bp[mb+1]; bi[2] = Bp[mb+2]; bi[3] = Bp[mb+3];
        #pragma unroll
        for (int sn = 0; sn < 4; ++sn) acc[sm][sn] = bi;
    }

    __syncthreads();

    const unsigned short* Wh = whi + (size_t)proj*16384;
    const unsigned short* Wl = wlo + (size_t)proj*16384;
    const int kq8  = q4 << 3;
    const int mrow = lane & 15;

    for (int pass = 0; pass < 3; ++pass) {
        const unsigned short* Wp = (pass == 2) ? Wl : Wh;
        const int xi = (pass == 1) ? 1 : 0;
        #pragma unroll
        for (int kc = 0; kc < 4; ++kc) {
            const int kb = kc << 5;
            short8 a[4], bf[4];
            #pragma unroll
            for (int sm = 0; sm < 4; ++sm) {
                const int m = wm*64 + sm*16 + mrow;
                a[sm] = *(const short8*)&Wp[(size_t)m*CC + kb + kq8];
            }
            #pragma unroll
            for (int sn = 0; sn < 4; ++sn) {
                const int n = wn*64 + sn*16 + mrow;
                const int scol = (kb + kq8) ^ (((n >> 3) & 7) << 3);
                bf[sn] = *(const short8*)&xT[xi][n][scol];
            }
            #pragma unroll
            for (int sm = 0; sm < 4; ++sm)
                #pragma unroll
                for (int sn = 0; sn < 4; ++sn)
                    acc[sm][sn] = __builtin_amdgcn_mfma_f32_16x16x32_bf16(
                        a[sm], bf[sn], acc[sm][sn], 0, 0, 0);
        }
    }

    float* op = qkv + (size_t)proj*BCHW + (size_t)b*CHW + npx;
    #pragma unroll
    for (int sm = 0; sm < 4; ++sm) {
        const int mb = wm*64 + sm*16 + q4*4;
        #pragma unroll
        for (int sn = 0; sn < 4; ++sn) {
            const int n = wn*64 + sn*16 + mrow;
            #pragma unroll
            for (int r = 0; r < 4; ++r)
                op[(size_t)(mb + r)*HWSZ + n] = acc[sm][sn][r];
        }
    }
}

// ================= Kernel 2: local attention v10 = v8 + barrier-free C ======
// Block = (b, h0..h0+1), 512 thr (8 waves), grid 256 (1 block/CU).
// EXACTLY R5's v8 (136.7us, locatt ~38, no spills) except ONE change:
// Phase C's per-chunk __syncthreads is deleted. Staging there is purely
// intra-wave (wave s writes v channels {2s,2s+1} and reads only those;
// halo zeros are written before the final Phase-B barrier and never
// touched again), so s_waitcnt lgkmcnt(0) suffices -- removes 8 block
// barriers AND their implicit vmcnt(0) drains of the v-prefetch.
// NO loop unrolling, single stg[4]/vreg[16] (v9's unroll+pingpong caused
// a VGPR spill: 141MB scratch writes, 2.5x regression).
__device__ __forceinline__ void load_chunk8(const float* __restrict__ src,
                                            int h0, int c0, float4* stg) {
    const int tid = threadIdx.x;
    #pragma unroll
    for (int i = 0; i < 4; ++i) {
        int f   = tid + (i << 9);           // 0..2047 = 16ch * 8r * 16quads
        int c   = f >> 7;
        int rem = f & 127;
        int r   = rem >> 4;
        int q4  = (rem & 15) << 2;
        int hh  = h0 - PAD + r;
        if ((unsigned)hh < (unsigned)HH_)
            stg[i] = *(const float4*)&src[(size_t)(c0 + c)*HWSZ + hh*WW_ + q4];
        else
            stg[i] = make_float4(0.f, 0.f, 0.f, 0.f);
    }
}

__global__ __launch_bounds__(512) void locatt(
    const float* __restrict__ qkv, float* __restrict__ out)
{
    __shared__ __align__(16) float smem[2*9792];    // A: +0/+9216, C: +0/+9792
    __shared__ float lg[2][NP][64];                 // 25088 B
    __shared__ float dn[2][64];

    const int blk = blockIdx.x;
    const int xs  = blk & 7;
    const int jj  = blk >> 3;
    const int b   = jj >> 2;
    const int h0  = (((xs << 2) | (jj & 3)) << 1);
    const int tid = threadIdx.x;
    const int s   = tid >> 6;      // wave 0..7
    const int lane = tid & 63;
    const int q16  = lane & 15;
    const int csub = lane >> 4;
    const int w4   = q16 << 2;
    const int w    = lane;         // phase C pixel

    const float* qp = qkv + (size_t)b*CHW;
    const float* kp = qkv + (size_t)BCHW + (size_t)b*CHW;
    const float* vp = qkv + (size_t)2*BCHW + (size_t)b*CHW;

    // zero k halo cols (0-3 & 68-71) in BOTH A-buffers; staging writes only
    // cols 4..67, so halos persist for all of phase A.
    {
        int buf = tid >> 8;                 // 0..1
        int t2  = tid & 255;
        int idx = t2 & 127;
        int c = idx >> 3, r = idx & 7;
        int col = (t2 < 128) ? 0 : 68;
        *(float4*)&smem[buf*9216 + (c*8 + r)*72 + col] =
            make_float4(0.f, 0.f, 0.f, 0.f);
    }

    const bool do0 = (s < 7);   // k-row s serves row0 p = s*7+dx
    const bool do1 = (s >= 1);  // and row1 p = (s-1)*7+dx

    float acc0[7][4], acc1[7][4];
    #pragma unroll
    for (int dx = 0; dx < 7; ++dx)
        #pragma unroll
        for (int j = 0; j < 4; ++j) { acc0[dx][j] = 0.f; acc1[dx][j] = 0.f; }

    float4 stg[4];
    load_chunk8(kp, h0, 0, stg);

    // -------- Phase A (double-buffered, 1 barrier/chunk) --------
    for (int ck = 0; ck < 8; ++ck) {
        float* ksb = smem + (ck & 1)*9216;      // [16][8][72]
        #pragma unroll
        for (int i = 0; i < 4; ++i) {
            int f   = tid + (i << 9);
            int c   = f >> 7;
            int rem = f & 127;
            int r   = rem >> 4;
            int q4  = (rem & 15) << 2;
            *(float4*)&ksb[(c*8 + r)*72 + 4 + q4] = stg[i];
        }
        __syncthreads();
        if (ck < 7) load_chunk8(kp, h0, (ck + 1) * 16, stg);

        const int c0 = ck << 4;
        #pragma unroll
        for (int ci4 = 0; ci4 < 4; ++ci4) {
            const int c = (ci4 << 2) + csub;
            const float* qc = qp + (size_t)(c0 + c)*HWSZ + h0*WW_ + w4;
            float4 q0v = do0 ? *(const float4*)qc
                             : make_float4(0.f, 0.f, 0.f, 0.f);
            float4 q1v = do1 ? *(const float4*)(qc + WW_)
                             : make_float4(0.f, 0.f, 0.f, 0.f);
            const float* krow = &ksb[(c*8 + s)*72];
            float4 ka  = *(const float4*)&krow[w4];
            float4 kb  = *(const float4*)&krow[w4 + 4];
            float4 kc2 = *(const float4*)&krow[w4 + 8];
            float kw[12] = {ka.x,ka.y,ka.z,ka.w, kb.x,kb.y,kb.z,kb.w,
                            kc2.x,kc2.y,kc2.z,kc2.w};
            float q0a[4] = {q0v.x,q0v.y,q0v.z,q0v.w};
            float q1a[4] = {q1v.x,q1v.y,q1v.z,q1v.w};
            #pragma unroll
            for (int dx = 0; dx < 7; ++dx)
                #pragma unroll
                for (int j = 0; j < 4; ++j) {
                    float kv = kw[j + dx + 1];   // spatial w4+j+dx-3
                    acc0[dx][j] = fmaf(q0a[j], kv, acc0[dx][j]);
                    acc1[dx][j] = fmaf(q1a[j], kv, acc1[dx][j]);
                }
        }
        // no trailing barrier: next chunk stores into the other buffer
    }

    // cross-csub reduce (lanes 0..15 <-> 16..31 <-> 32..47 <-> 48..63)
    #pragma unroll
    for (int dx = 0; dx < 7; ++dx)
        #pragma unroll
        for (int j = 0; j < 4; ++j) {
            acc0[dx][j] += __shfl_xor(acc0[dx][j], 16, 64);
            acc0[dx][j] += __shfl_xor(acc0[dx][j], 32, 64);
            acc1[dx][j] += __shfl_xor(acc1[dx][j], 16, 64);
            acc1[dx][j] += __shfl_xor(acc1[dx][j], 32, 64);
        }
    // write lg (b128), distributed: csub writes dx with (dx&3)==csub
    #pragma unroll
    for (int dx = 0; dx < 7; ++dx) {
        if ((dx & 3) == csub) {
            if (do0) *(float4*)&lg[0][s*7 + dx][w4] =
                make_float4(acc0[dx][0], acc0[dx][1], acc0[dx][2], acc0[dx][3]);
            if (do1) *(float4*)&lg[1][(s-1)*7 + dx][w4] =
                make_float4(acc1[dx][0], acc1[dx][1], acc1[dx][2], acc1[dx][3]);
        }
    }

    // prefetch v chunk 0 (wave s -> chunk channels {2s,2s+1}, all 8 rows)
    float vreg[16];
    {
        #pragma unroll
        for (int i = 0; i < 16; ++i) {
            int c  = 2*s + (i >> 3);
            int r  = i & 7;
            int hh = h0 - PAD + r;
            vreg[i] = ((unsigned)hh < (unsigned)HH_)
                      ? vp[(size_t)c*HWSZ + hh*WW_ + w] : 0.f;
        }
    }
    __syncthreads();

    // -------- Phase B: two softmaxes (OOB logits exactly 0, included) ------
    if (tid < 128) {
        const int r = tid >> 6, px = tid & 63;
        float tv[NP];
        float m = -1e30f;
        #pragma unroll
        for (int p = 0; p < NP; ++p) { tv[p] = lg[r][p][px]; m = fmaxf(m, tv[p]); }
        float d = 0.f;
        #pragma unroll
        for (int p = 0; p < NP; ++p) {
            float e = __expf(tv[p] - m);
            d += e;
            lg[r][p][px] = e;
        }
        dn[r][px] = 1.f / d;
    } else {
        // zero vT halo cols {0..3, 68..71} x 8r x 16 slots in BOTH C-buffers
        // (2048 floats over threads 128..511); never touched in phase C.
        int t = tid - 128;
        for (int i = t; i < 2048; i += 384) {
            int buf  = i >> 10;
            int rem1 = i & 1023;
            int r    = rem1 >> 7;
            int rem  = rem1 & 127;
            int colg = rem >> 4;
            int col  = (colg < 4) ? colg : (64 + colg);
            smem[buf*9792 + r*1224 + col*17 + (rem & 15)] = 0.f;
        }
    }
    __syncthreads();

    // -------- Phase C (barrier-free: staging is intra-wave only) --------
    float a0[NP], a1[NP];
    const float sc0 = dn[0][w], sc1 = dn[1][w];
    #pragma unroll
    for (int p = 0; p < NP; ++p) a0[p] = lg[0][p][w] * sc0;
    #pragma unroll
    for (int p = 0; p < NP; ++p) a1[p] = lg[1][p][w] * sc1;

    for (int ck = 0; ck < 8; ++ck) {
        float* vb = smem + (ck & 1)*9792;       // vT[8][72][17]
        // store vreg -> vT[r][4+w][c]  (stride 17 across lanes: conflict-free)
        #pragma unroll
        for (int i = 0; i < 16; ++i) {
            int c = 2*s + (i >> 3);
            int r = i & 7;
            vb[r*1224 + (4 + w)*17 + c] = vreg[i];
        }
        if (ck < 7) {
            int c0v = (ck + 1) << 4;
            #pragma unroll
            for (int i = 0; i < 16; ++i) {
                int c  = 2*s + (i >> 3);
                int r  = i & 7;
                int hh = h0 - PAD + r;
                vreg[i] = ((unsigned)hh < (unsigned)HH_)
                          ? vp[(size_t)(c0v + c)*HWSZ + hh*WW_ + w] : 0.f;
            }
        }
        // intra-wave LDS visibility only (own wave's ds_writes): the
        // compiler also orders the aliasing ds_read/ds_write pair itself.
        asm volatile("s_waitcnt lgkmcnt(0)" ::: "memory");

        float y0a = 0.f, y0b = 0.f, y1a = 0.f, y1b = 0.f;
        #pragma unroll
        for (int r = 0; r < 8; ++r) {
            const float* vbase = &vb[r*1224 + (1 + w)*17 + 2*s];
            #pragma unroll
            for (int dx = 0; dx < 7; ++dx) {
                float va  = vbase[17*dx];       // channel 2s
                float vb2 = vbase[17*dx + 1];   // channel 2s+1 (ds_read2 pair)
                if (r < 7) {
                    float aw = a0[r*7 + dx];
                    y0a = fmaf(aw, va, y0a); y0b = fmaf(aw, vb2, y0b);
                }
                if (r >= 1) {
                    float aw = a1[(r-1)*7 + dx];
                    y1a = fmaf(aw, va, y1a); y1b = fmaf(aw, vb2, y1b);
                }
            }
        }
        float* op = out + (size_t)b*CHW + (size_t)(ck*16 + 2*s)*HWSZ
                        + (size_t)h0*WW_ + w;
        op[0]          = y0a;   // c=2s,   row h0
        op[WW_]        = y1a;   // c=2s,   row h0+1
        op[HWSZ]       = y0b;   // c=2s+1, row h0
        op[HWSZ + WW_] = y1b;   // c=2s+1, row h0+1
        // no barrier: each wave re-stages only its own channels
    }
}

extern "C" void kernel_launch(void* const* d_in, const int* in_sizes, int n_in,
                              void* d_out, int out_size, void* d_ws, size_t ws_size,
                              hipStream_t stream) {
    const float* x  = (const float*)d_in[0];
    const float* Wq = (const float*)d_in[1];
    const float* bq = (const float*)d_in[2];
    const float* Wk = (const float*)d_in[3];
    const float* bk = (const float*)d_in[4];
    const float* Wv = (const float*)d_in[5];
    const float* bv = (const float*)d_in[6];
    float* out = (float*)d_out;
    float* qkv = (float*)d_ws;   // 3*BCHW*4 = 50.3 MB scratch

    // d_out doubles as scratch for bf16 W (196 KB); fully overwritten by
    // locatt afterwards (stream-ordered), safe under re-poisoning.
    unsigned short* whi = (unsigned short*)d_out;
    unsigned short* wlo = whi + 3*16384;

    prep_w  <<<192, 256, 0, stream>>>(Wq, Wk, Wv, whi, wlo);
    qkv_mfma<<<dim3(256, 3), 256, 0, stream>>>(x, whi, wlo, bq, bk, bv, qkv);
    locatt  <<<256, 512, 0, stream>>>(qkv, out);
}